// Round 15
// baseline (490.309 us; speedup 1.0000x reference)
//
#include <hip/hip_runtime.h>

typedef unsigned short u16;
typedef u16 u16x8 __attribute__((ext_vector_type(8)));
typedef float f32x4v __attribute__((ext_vector_type(4)));
typedef __bf16 bf16x8 __attribute__((ext_vector_type(8)));

// ---------- helpers ----------
__device__ __forceinline__ u16 f2bf(float f) {
  unsigned u = __builtin_bit_cast(unsigned, f);
  u += 0x7fffu + ((u >> 16) & 1u);  // round-to-nearest-even
  return (u16)(u >> 16);
}
__device__ __forceinline__ float bf2f(u16 b) {
  return __builtin_bit_cast(float, (unsigned)b << 16);
}

// ---------- fp32 -> bf16 conversion ----------
__global__ __launch_bounds__(256) void cvt_f32_bf16(const float* __restrict__ in,
                                                    u16* __restrict__ out, long n) {
  long i0 = ((long)blockIdx.x * 256 + threadIdx.x) * 8;
  long stride = (long)gridDim.x * 256 * 8;
  for (long i = i0; i < n; i += stride) {
    float4 a = *(const float4*)(in + i);
    float4 b = *(const float4*)(in + i + 4);
    u16x8 o;
    o[0] = f2bf(a.x); o[1] = f2bf(a.y); o[2] = f2bf(a.z); o[3] = f2bf(a.w);
    o[4] = f2bf(b.x); o[5] = f2bf(b.y); o[6] = f2bf(b.z); o[7] = f2bf(b.w);
    *(u16x8*)(out + i) = o;
  }
}

// ---------- 256x256 GEMM, 8-phase, 1 barrier/phase, COMPILER-COUNTED lgkm ----------
// Change vs R14 (single variable): the manual "lgkmcnt(0)+sched_barrier" full-drain
// after each barrier is REMOVED. ds_reads are compiler-emitted; compiler inserts
// progressive lgkmcnt(N) per MFMA operand -> MFMA issue overlaps LDS drain (m97
// finding; m141: order-pinning defeats the scheduler).
// Correctness: RAW anchored by vmcnt-asm memory clobbers (loads can't hoist above);
// WAR: phase-p reads are consumed by phase-p MFMAs before the next s_barrier issues
// (in-order issue), and sched_barrier(0) right after each barrier blocks compile-time
// hoisting of stages/reads across it.
// Stage schedule (slot <- tile): p1:B(d1,h1)<-t1 p2:A(d1,h0)<-t1 p3:A(d1,h1)<-t1
//   p4:B(d0,h0)<-t2 p5:B(d0,h1)<-t2 p6:A(d0,h0)<-t2 p7:A(d0,h1)<-t2 p8:B(d1,h0)<-t3.
// vmcnt(2) before BAR at p4 (t1 landed) / p8 (t2 landed); FIFO-exact, single class.
template <int EPI>
__global__ __launch_bounds__(512, 2) void gemm256(
    const u16* __restrict__ A, long lda, long bsA,
    const u16* __restrict__ B, long ldb, long bsB,
    void* __restrict__ Cv, long ldc, long bsC, int K,
    const int* __restrict__ maskp, float scale,
    const float* __restrict__ bias, float* __restrict__ aux) {
  extern __shared__ u16 sm[];
  const int t = threadIdx.x;
  const int lane = t & 63;
  const int w8 = t >> 6;
  const int wr = w8 >> 2;  // 0..1
  const int wc = w8 & 3;   // 0..3

  // T1: bijective XCD-chunked remap (all grids here have nwg % 8 == 0)
  const int nwg = gridDim.x * gridDim.y * gridDim.z;
  int flat = blockIdx.x + gridDim.x * (blockIdx.y + gridDim.y * blockIdx.z);
  int nid = (flat & 7) * (nwg >> 3) + (flat >> 3);
  const int bx = nid % gridDim.x;
  const int by = (nid / gridDim.x) % gridDim.y;
  const int bz = nid / (gridDim.x * gridDim.y);

  // staging sources: thread t covers row sr (and sr+64) of a half, chunk (t&7)^(sr&7)
  const int sr = t >> 3;
  const int sc = ((t & 7) ^ (sr & 7)) * 8;
  const u16* gA_ = A + (long)bz * bsA + ((long)bx * 256 + sr) * lda + sc;
  const u16* gB_ = B + (long)bz * bsB + ((long)by * 256 + sr) * ldb + sc;

#define GLDS(gptr, lidx)                                                        \
  __builtin_amdgcn_global_load_lds(                                             \
      (const __attribute__((address_space(1))) void*)(gptr),                    \
      (__attribute__((address_space(3))) void*)(sm + (lidx)), 16, 0, 0)

#define STG_A(d, h, kt)                                                         \
  do {                                                                          \
    const int bb = ((d)*2 + (h)) * 8192;                                        \
    const long ko = (long)(kt)*64;                                              \
    GLDS(gA_ + (long)((h)*128) * lda + ko, bb + t * 8);                         \
    GLDS(gA_ + (long)((h)*128 + 64) * lda + ko, bb + 4096 + t * 8);             \
  } while (0)
#define STG_B(d, h, kt)                                                         \
  do {                                                                          \
    const int bb = 32768 + ((d)*2 + (h)) * 8192;                                \
    const long ko = (long)(kt)*64;                                              \
    GLDS(gB_ + (long)((h)*128) * ldb + ko, bb + t * 8);                         \
    GLDS(gB_ + (long)((h)*128 + 64) * ldb + ko, bb + 4096 + t * 8);             \
  } while (0)

  f32x4v acc[8][4];
#pragma unroll
  for (int i = 0; i < 8; ++i)
#pragma unroll
    for (int j = 0; j < 4; ++j) acc[i][j] = (f32x4v){0.f, 0.f, 0.f, 0.f};

  // frag read offsets (u16): row lr, k-chunk c, phys = c ^ (lr&7)
  const int g = lane >> 4;
  const int s3 = lane & 7;
  const int rl = lane & 15;
  const int ox0 = ((0 * 4 + g) ^ s3) * 8;
  const int ox1 = ((1 * 4 + g) ^ s3) * 8;
  const int oa0 = rl * 64 + ox0, oa1 = rl * 64 + ox1;
  const int obb = (wc & 1) * 4096 + rl * 64;

  bf16x8 af[4][2], bq[4][2];

#define RD_A(d, rh)                                                             \
  do {                                                                          \
    const int ab = ((d)*2 + wr) * 8192 + (rh)*4096;                             \
    _Pragma("unroll") for (int j = 0; j < 4; ++j) {                             \
      af[j][0] = *(const bf16x8*)(sm + ab + j * 1024 + oa0);                    \
      af[j][1] = *(const bf16x8*)(sm + ab + j * 1024 + oa1);                    \
    }                                                                           \
  } while (0)
#define RD_B(d, ch)                                                             \
  do {                                                                          \
    const int bb = 32768 + ((d)*2 + (wc >> 1)) * 8192 + obb;                    \
    _Pragma("unroll") for (int i = 0; i < 2; ++i) {                             \
      bq[(ch)*2 + i][0] = *(const bf16x8*)(sm + bb + ((ch)*2 + i) * 1024 + ox0);\
      bq[(ch)*2 + i][1] = *(const bf16x8*)(sm + bb + ((ch)*2 + i) * 1024 + ox1);\
    }                                                                           \
  } while (0)
#define DO_MFMA(rh, ch)                                                         \
  do {                                                                          \
    __builtin_amdgcn_s_setprio(1);                                              \
    _Pragma("unroll") for (int j = 0; j < 4; ++j)                               \
        _Pragma("unroll") for (int i = 0; i < 2; ++i) {                         \
      acc[(rh)*4 + j][(ch)*2 + i] = __builtin_amdgcn_mfma_f32_16x16x32_bf16(    \
          af[j][0], bq[(ch)*2 + i][0], acc[(rh)*4 + j][(ch)*2 + i], 0, 0, 0);   \
      acc[(rh)*4 + j][(ch)*2 + i] = __builtin_amdgcn_mfma_f32_16x16x32_bf16(    \
          af[j][1], bq[(ch)*2 + i][1], acc[(rh)*4 + j][(ch)*2 + i], 0, 0, 0);   \
    }                                                                           \
    __builtin_amdgcn_s_setprio(0);                                              \
  } while (0)

#define BAR __builtin_amdgcn_s_barrier()
#define SCHED __builtin_amdgcn_sched_barrier(0)
#define VM(n) asm volatile("s_waitcnt vmcnt(" #n ")" ::: "memory")

  const int nw = K >> 7;  // windows of 2 K-tiles

  // ---- prologue: t0 all (8) + t1.B0 (2); VM(2) -> t0 landed ----
  STG_B(0, 0, 0); STG_B(0, 1, 0);
  STG_A(0, 0, 0); STG_A(0, 1, 0);
  STG_B(1, 0, 1);
  VM(2);
  BAR; SCHED;

  for (int w = 0; w < nw; ++w) {
    const int kt1 = 2 * w + 1;
    const bool nx = (w + 1 < nw);
    // p1: t0 q(0,0) ; stage t1.B1
    RD_A(0, 0); RD_B(0, 0);
    STG_B(1, 1, kt1);
    BAR; SCHED;
    DO_MFMA(0, 0);
    // p2: t0 q(0,1) ; stage t1.A0
    RD_B(0, 1);
    STG_A(1, 0, kt1);
    BAR; SCHED;
    DO_MFMA(0, 1);
    // p3: t0 q(1,1) ; stage t1.A1
    RD_A(0, 1);
    STG_A(1, 1, kt1);
    BAR; SCHED;
    DO_MFMA(1, 1);
    // p4: t0 q(1,0) ; stage t2.B0 ; VM -> t1 landed
    if (nx) STG_B(0, 0, kt1 + 1);
    if (nx) VM(2); else VM(0);
    BAR; SCHED;
    DO_MFMA(1, 0);
    // p5: t1 q(0,0) ; stage t2.B1
    RD_A(1, 0); RD_B(1, 0);
    if (nx) STG_B(0, 1, kt1 + 1);
    BAR; SCHED;
    DO_MFMA(0, 0);
    // p6: t1 q(0,1) ; stage t2.A0
    RD_B(1, 1);
    if (nx) STG_A(0, 0, kt1 + 1);
    BAR; SCHED;
    DO_MFMA(0, 1);
    // p7: t1 q(1,1) ; stage t2.A1
    RD_A(1, 1);
    if (nx) STG_A(0, 1, kt1 + 1);
    BAR; SCHED;
    DO_MFMA(1, 1);
    // p8: t1 q(1,0) ; stage t3.B0 ; VM -> t2 landed
    if (nx) {
      STG_B(1, 0, kt1 + 2);
      VM(2);
    }
    BAR; SCHED;
    DO_MFMA(1, 0);
  }
#undef STG_A
#undef STG_B
#undef GLDS

  // ---- epilogue: C/D layout col = lane&15, row = (lane>>4)*4 + reg ----
  const long row0 = (long)bx * 256 + wr * 128;
  const long col0 = (long)by * 256 + wc * 64;
  const int l4 = lane >> 4;
  const int cl = lane & 15;
  if constexpr (EPI == 0) {
    u16* C = (u16*)Cv + (long)bz * bsC;
    const int* mrow = maskp + (long)bz * 2048;
    int mk4[4];
#pragma unroll
    for (int fc = 0; fc < 4; ++fc) mk4[fc] = mrow[col0 + fc * 16 + cl];
#pragma unroll
    for (int fr = 0; fr < 8; ++fr) {
#pragma unroll
      for (int r = 0; r < 4; ++r) {
        long row = row0 + fr * 16 + l4 * 4 + r;
        float s = 0.f;
#pragma unroll
        for (int fc = 0; fc < 4; ++fc) {
          long col = col0 + fc * 16 + cl;
          float e = mk4[fc] ? __expf(acc[fr][fc][r] * scale + 1e-13f) : 1.0f;
          u16 eb = f2bf(e);
          C[row * ldc + col] = eb;
          s += bf2f(eb);
        }
        s += __shfl_xor(s, 1);
        s += __shfl_xor(s, 2);
        s += __shfl_xor(s, 4);
        s += __shfl_xor(s, 8);
        if (cl == 0) aux[((long)bz * 2048 + row) * 32 + by * 4 + wc] = s;
      }
    }
  } else if constexpr (EPI == 1) {
    u16* C = (u16*)Cv + (long)bz * bsC;
    const float* linv = aux + (long)bz * 2048;
#pragma unroll
    for (int fr = 0; fr < 8; ++fr) {
#pragma unroll
      for (int r = 0; r < 4; ++r) {
        long row = row0 + fr * 16 + l4 * 4 + r;
        float li = linv[row];
#pragma unroll
        for (int fc = 0; fc < 4; ++fc) {
          long col = col0 + fc * 16 + cl;
          C[row * ldc + col] = f2bf(acc[fr][fc][r] * li);
        }
      }
    }
  } else {
    float* C = (float*)Cv;
#pragma unroll
    for (int fc = 0; fc < 4; ++fc) {
      long col = col0 + fc * 16 + cl;
      float bj = bias[col];
#pragma unroll
      for (int fr = 0; fr < 8; ++fr) {
        long row = row0 + fr * 16 + l4 * 4;
#pragma unroll
        for (int r = 0; r < 4; ++r) C[(row + r) * ldc + col] = acc[fr][fc][r] + bj;
      }
    }
  }
}

// ---------- per-row 1/sum of 32 partials ----------
__global__ __launch_bounds__(256) void rowsum_inv(const float* __restrict__ part,
                                                  float* __restrict__ linv) {
  int i = blockIdx.x * 256 + threadIdx.x;  // 0..32767
  const float4* p = (const float4*)(part + (long)i * 32);
  float s = 0.f;
#pragma unroll
  for (int j = 0; j < 8; ++j) {
    float4 v = p[j];
    s += (v.x + v.y) + (v.z + v.w);
  }
  linv[i] = 1.0f / s;
}

// ---------- launcher ----------
extern "C" void kernel_launch(void* const* d_in, const int* in_sizes, int n_in,
                              void* d_out, int out_size, void* d_ws, size_t ws_size,
                              hipStream_t stream) {
  const float* Q = (const float*)d_in[0];
  const float* K = (const float*)d_in[1];
  const float* V = (const float*)d_in[2];
  const int* mask = (const int*)d_in[3];
  const float* W = (const float*)d_in[4];
  const float* bias = (const float*)d_in[5];

  const long NQ = 16L * 2048 * 1024;
  u16* Qb = (u16*)d_ws;
  u16* Kb = Qb + NQ;
  u16* Vb = Kb + NQ;
  u16* Wb = Vb + NQ;
  u16* Eb = Wb + 1024L * 1024;                     // [16][2048][2048] bf16
  float* Part = (float*)(Eb + 16L * 2048 * 2048);  // [16*2048][32] f32
  float* Linv = Part + 32768L * 32;                // [16*2048] f32
  u16* R = Qb;                                     // alias: Qb dead after GEMM1

  cvt_f32_bf16<<<2048, 256, 0, stream>>>(Q, Qb, NQ);
  cvt_f32_bf16<<<2048, 256, 0, stream>>>(K, Kb, NQ);
  cvt_f32_bf16<<<2048, 256, 0, stream>>>(V, Vb, NQ);
  cvt_f32_bf16<<<512, 256, 0, stream>>>(W, Wb, 1024L * 1024);

  // E = exp(QK^T*scale+1e-13) (masked cols -> 1.0), bf16 + per-row partial sums
  gemm256<0><<<dim3(8, 8, 16), 512, 131072, stream>>>(
      Qb, 1024, 2048L * 1024, Kb, 1024, 2048L * 1024,
      Eb, 2048, 2048L * 2048, 1024, mask, 0.03125f, nullptr, Part);

  rowsum_inv<<<128, 256, 0, stream>>>(Part, Linv);

  // R = (E V^T) * Linv[row], bf16
  gemm256<1><<<dim3(8, 4, 16), 512, 131072, stream>>>(
      Eb, 2048, 2048L * 2048, Vb, 2048, 1024L * 2048,
      R, 1024, 2048L * 1024, 2048, nullptr, 1.f, nullptr, Linv);

  // out = R W^T + bias
  gemm256<2><<<dim3(128, 4, 1), 512, 131072, stream>>>(
      R, 1024, 0, Wb, 1024, 0,
      d_out, 1024, 0, 1024, nullptr, 1.f, bias, nullptr);
}